// Round 1
// baseline (82.097 us; speedup 1.0000x reference)
//
#include <hip/hip_runtime.h>
#include <float.h>

#define OUTP 7
#define NCH 256
#define FH 50
#define FW 50

__global__ __launch_bounds__(256) void roi_pool_kernel(
    const float* __restrict__ features,   // (B,256,50,50)
    const float* __restrict__ cat_rois,   // (N,5): im,x1,y1,x2,y2
    float* __restrict__ out,              // (N,256,7,7)
    int total)
{
    int idx = blockIdx.x * blockDim.x + threadIdx.x;
    if (idx >= total) return;

    int j = idx % OUTP;
    int t = idx / OUTP;
    int i = t % OUTP;
    t /= OUTP;
    int c = t % NCH;
    int n = t / NCH;

    const float* r5 = cat_rois + n * 5;
    int im = (int)rintf(r5[0]);
    int x1 = (int)rintf(r5[1] * 0.0625f);
    int y1 = (int)rintf(r5[2] * 0.0625f);
    int x2 = (int)rintf(r5[3] * 0.0625f);
    int y2 = (int)rintf(r5[4] * 0.0625f);

    int h = y2 - y1 + 1;
    int w = x2 - x1 + 1;

    int ys = i * h / OUTP + y1;
    int ye = ((i + 1) * h + OUTP - 1) / OUTP + y1;
    int xs = j * w / OUTP + x1;
    int xe = ((j + 1) * w + OUTP - 1) / OUTP + x1;

    // match reference mask semantics (indices restricted to [0,H)x[0,W))
    ys = max(ys, 0);  ye = min(ye, FH);
    xs = max(xs, 0);  xe = min(xe, FW);

    const float* base = features + ((size_t)(im * NCH + c)) * (FH * FW);

    float m = -FLT_MAX;
    for (int r = ys; r < ye; ++r) {
        const float* row = base + r * FW;
        for (int x = xs; x < xe; ++x) {
            m = fmaxf(m, row[x]);
        }
    }
    out[idx] = m;
}

extern "C" void kernel_launch(void* const* d_in, const int* in_sizes, int n_in,
                              void* d_out, int out_size, void* d_ws, size_t ws_size,
                              hipStream_t stream) {
    const float* features = (const float*)d_in[0];
    const float* cat_rois = (const float*)d_in[1];
    float* out = (float*)d_out;

    int total = out_size;  // N*256*7*7
    int block = 256;
    int grid = (total + block - 1) / block;
    roi_pool_kernel<<<grid, block, 0, stream>>>(features, cat_rois, out, total);
}